// Round 7
// baseline (726.178 us; speedup 1.0000x reference)
//
#include <hip/hip_runtime.h>
#include <math.h>

typedef __attribute__((ext_vector_type(8))) short short8;
typedef __attribute__((ext_vector_type(4))) float f32x4;

#define LRELU(x) ((x) > 0.0f ? (x) : 0.01f * (x))

__device__ __forceinline__ float bf2f(unsigned short h) {
    return __uint_as_float(((unsigned int)h) << 16);
}
__device__ __forceinline__ unsigned short f2bf(float f) {
    unsigned int u = __float_as_uint(f);
    return (unsigned short)((u + 0x7FFFu + ((u >> 16) & 1u)) >> 16);
}
__device__ __forceinline__ float2 stats_from(const float* sums, int b, float count) {
    float s = sums[2 * b], q = sums[2 * b + 1];
    float mean = s / count;
    float var = (q - s * s / count) / (count - 1.0f);  // ddof=1
    var = fmaxf(var, 0.0f);
    return make_float2(mean, 1.0f / (sqrtf(var) + 1e-5f));
}
// init pattern 0xFFFFFFFF (-NaN): positives via signed max, negatives via unsigned min
__device__ __forceinline__ void atomicMaxF(float* a, float v) {
    if (v >= 0.0f) atomicMax((int*)a, __float_as_int(v));
    else           atomicMin((unsigned int*)a, __float_as_uint(v));
}

// w [O][Cin][3] f32  ->  wq [O][3*Cin] bf16 with k' = j*Cin + c
__global__ void prep_weights(const float* __restrict__ w, unsigned short* __restrict__ wq,
                             int O, int Cin)
{
    const int K = 3 * Cin, total = O * K;
    for (int i = blockIdx.x * blockDim.x + threadIdx.x; i < total;
         i += gridDim.x * blockDim.x) {
        int o = i / K, kp = i - o * K;
        int j = kp / Cin, c = kp - j * Cin;
        wq[i] = f2bf(w[(o * Cin + c) * 3 + j]);
    }
}

// data [128][64][1024] f32 -> xT [nB][1024][64] bf16 (tower select on b>=128)
__global__ __launch_bounds__(256) void transpose_in(const float* __restrict__ inA,
                                                    const float* __restrict__ inB,
                                                    unsigned short* __restrict__ xT)
{
    const int b = blockIdx.y, n0 = blockIdx.x * 64;
    const float* in = (b >= 128 ? inB : inA) + ((size_t)(b & 127) * 64) * 1024;
    const int tid = threadIdx.x;
    __shared__ float tile[64][65];
    const int nn = tid & 63, cw = tid >> 6;
#pragma unroll
    for (int i = 0; i < 16; i++) {
        int c = i * 4 + cw;
        tile[c][nn] = in[(size_t)c * 1024 + n0 + nn];
    }
    __syncthreads();
    const int n = tid >> 2, cp = (tid & 3) * 16;
    unsigned int pk[8];
#pragma unroll
    for (int i = 0; i < 8; i++) {
        unsigned short lo = f2bf(tile[cp + 2 * i][n]);
        unsigned short hi = f2bf(tile[cp + 2 * i + 1][n]);
        pk[i] = (unsigned int)lo | ((unsigned int)hi << 16);
    }
    unsigned short* dst = xT + ((size_t)b * 1024 + n0 + n) * 64 + cp;
    uint4 v0 = {pk[0], pk[1], pk[2], pk[3]};
    uint4 v1 = {pk[4], pk[5], pk[6], pk[7]};
    *(uint4*)dst = v0;
    *(uint4*)(dst + 8) = v1;
}

// MFMA gather-conv, register-staged pipelined K-loop.
// Chunk kc+1's buffer loads are issued right after chunk kc's ds_writes, so the
// (random-gather) load latency overlaps the barrier + MFMA of chunk kc. Pure
// register staging => s_barrier needs no vmcnt(0) drain; prefetch stays in flight.
// __launch_bounds__(256, 2): 2 waves/EU target -> VGPR cap 256 so the 32 staging
// VGPRs live across the MFMA block allocate instead of spilling (R5/R6 bug:
// default heuristic capped at 88 VGPRs -> 520 MB of per-chunk scratch traffic).
template <int BM, bool POOL>
__global__ __launch_bounds__(256, 2) void conv_mfma(
    const unsigned short* __restrict__ xT,   // [nB][1024][Cin] bf16
    const int* __restrict__ idxA,            // [128][3069]
    const int* __restrict__ idxB,
    const unsigned short* __restrict__ wq,   // [O][K] bf16 (k'=j*Cin+c)
    const float* __restrict__ bias,          // [O] f32
    unsigned short* __restrict__ out,        // [nB][1024][O] bf16 (unused if POOL)
    float* __restrict__ sums,                // [nB][2] accum
    float* __restrict__ pmax,                // [nB][64] (POOL only)
    int Cin, int cinShift, int O, int K)
{
    constexpr int WM = BM / 2, MT = WM / 16;
    constexpr int NW = (BM == 128) ? 4 : 2;      // 16B packets of wt per thread
    const int b   = blockIdx.x;
    const int o0  = blockIdx.y * BM;
    const int nt0 = blockIdx.z << 7;
    const int tid = threadIdx.x;
    const int lane = tid & 63, wave = tid >> 6;
    const int wo = wave & 1, wn = wave >> 1;
    const int quad = lane >> 4, l15 = lane & 15;
    const int blkid = lane & 7;

    __shared__ __align__(16) unsigned short wt[BM * 64];
    __shared__ __align__(16) unsigned short gt[128 * 64];

    f32x4 acc[MT][4];
#pragma unroll
    for (int i = 0; i < MT; i++)
#pragma unroll
        for (int t = 0; t < 4; t++) acc[i][t] = (f32x4){0.f, 0.f, 0.f, 0.f};

    const unsigned short* xTb = xT + (((size_t)b) << 10) * (size_t)Cin;
    const int* idxb = (b >= 128 ? idxB : idxA) + (size_t)(b & 127) * 3069;

    // --- staging mapping ---
    const int gr = tid >> 1, gh = tid & 1;       // gt row (n), 32-elem half
    int s3[3];
    {
        int n = nt0 + gr;
        int t0 = (n == 0) ? 0 : (n - 1);         // n==0 row is garbage, zeroed later
        s3[0] = idxb[3 * t0]; s3[1] = idxb[3 * t0 + 1]; s3[2] = idxb[3 * t0 + 2];
    }
    const int wr   = (BM == 128) ? (tid >> 1) : (tid >> 2);  // wt row (o)
    const int wseg = (BM == 128) ? (tid & 1) : (tid & 3);    // segment of NW packets
    const unsigned short* wrow = wq + (size_t)(o0 + wr) * K + wseg * (NW * 8);
    const int gswz = gr & 7, wswz = wr & 7;

    uint4 gA[4], wA[NW];
    auto loadChunk = [&](int kc) {
        const int k64 = kc << 6;
        const int j  = k64 >> cinShift;
        const int c0 = k64 & (Cin - 1);
        const int src = (j == 0) ? s3[0] : ((j == 1) ? s3[1] : s3[2]);
        const uint4* gp = (const uint4*)(xTb + (size_t)src * Cin + c0 + gh * 32);
#pragma unroll
        for (int i = 0; i < 4; i++) gA[i] = gp[i];
        const uint4* wp = (const uint4*)(wrow + k64);
#pragma unroll
        for (int i = 0; i < NW; i++) wA[i] = wp[i];
    };
    auto stage = [&]() {
#pragma unroll
        for (int i = 0; i < 4; i++) {
            const int ph = (gh * 4 + i) ^ gswz;          // XOR addr swizzle only
            *(uint4*)&gt[gr * 64 + ph * 8] = gA[i];
        }
#pragma unroll
        for (int i = 0; i < NW; i++) {
            const int ph = (wseg * NW + i) ^ wswz;
            *(uint4*)&wt[wr * 64 + ph * 8] = wA[i];
        }
    };

    const int nChunks = K >> 6;
    loadChunk(0);
    for (int kc = 0; kc < nChunks; ++kc) {
        if (kc) __syncthreads();        // prior chunk's readers done
        stage();                        // waits in-flight loads, writes LDS
        if (kc + 1 < nChunks) loadChunk(kc + 1);  // issue next loads early
        __syncthreads();                // staged data visible
#pragma unroll
        for (int st = 0; st < 2; ++st) {
            short8 af[MT], bfv[4];
            const int qb = st * 4 + quad;
#pragma unroll
            for (int i = 0; i < MT; i++) {
                const int orow = wo * WM + i * 16 + l15;
                af[i] = *(const short8*)&wt[orow * 64 + ((qb ^ blkid) << 3)];
            }
#pragma unroll
            for (int t = 0; t < 4; t++) {
                const int nrow = wn * 64 + t * 16 + l15;
                bfv[t] = *(const short8*)&gt[nrow * 64 + ((qb ^ blkid) << 3)];
            }
#pragma unroll
            for (int i = 0; i < MT; i++)
#pragma unroll
                for (int t = 0; t < 4; t++)
                    acc[i][t] = __builtin_amdgcn_mfma_f32_16x16x32_bf16(
                        af[i], bfv[t], acc[i][t], 0, 0, 0);
        }
    }

    // epilogue: bias, zero col 0, store (unless POOL), fused stats, fused max-pool
    float lsum = 0.f, lsq = 0.f;
#pragma unroll
    for (int i = 0; i < MT; i++) {
        const int ob = o0 + wo * WM + i * 16 + quad * 4;
        const float4 bv = *(const float4*)(bias + ob);
        float mx[4] = {-1e30f, -1e30f, -1e30f, -1e30f};
#pragma unroll
        for (int t = 0; t < 4; t++) {
            const int n = nt0 + wn * 64 + t * 16 + l15;
            float v0 = acc[i][t][0] + bv.x;
            float v1 = acc[i][t][1] + bv.y;
            float v2 = acc[i][t][2] + bv.z;
            float v3 = acc[i][t][3] + bv.w;
            if (n == 0) { v0 = v1 = v2 = v3 = 0.f; }
            lsum += v0 + v1 + v2 + v3;
            lsq  += v0 * v0 + v1 * v1 + v2 * v2 + v3 * v3;
            if (POOL) {
                mx[0] = fmaxf(mx[0], v0); mx[1] = fmaxf(mx[1], v1);
                mx[2] = fmaxf(mx[2], v2); mx[3] = fmaxf(mx[3], v3);
            } else {
                ushort4 pk;
                pk.x = f2bf(v0); pk.y = f2bf(v1); pk.z = f2bf(v2); pk.w = f2bf(v3);
                *(ushort4*)&out[((size_t)b * 1024 + n) * O + ob] = pk;
            }
        }
        if (POOL) {
#pragma unroll
            for (int r = 0; r < 4; r++) {
                float m = mx[r];
#pragma unroll
                for (int off = 1; off < 16; off <<= 1)
                    m = fmaxf(m, __shfl_xor(m, off));
                if (l15 == 0) atomicMaxF(&pmax[(size_t)b * 64 + ob + r], m);
            }
        }
    }
#pragma unroll
    for (int off = 32; off > 0; off >>= 1) {
        lsum += __shfl_down(lsum, off);
        lsq  += __shfl_down(lsq, off);
    }
    float* red = (float*)wt;  // wt dead after K-loop
    if (lane == 0) { red[wave] = lsum; red[4 + wave] = lsq; }
    __syncthreads();
    if (tid == 0) {
        atomicAdd(&sums[2 * b + 0], red[0] + red[1] + red[2] + red[3]);
        atomicAdd(&sums[2 * b + 1], red[4] + red[5] + red[6] + red[7]);
    }
}

// in-place: act = lrelu((act - mean) * inv)
__global__ __launch_bounds__(256) void normalize_act(unsigned short* __restrict__ act,
                                                     const float* __restrict__ sums,
                                                     float count, int C)
{
    const int b = blockIdx.y;
    const float2 s = stats_from(sums, b, count);
    const float a = s.y, c2 = -s.x * s.y;
    size_t off = (((size_t)b << 10) * C) + ((size_t)blockIdx.x * 2048) + (size_t)threadIdx.x * 8;
    uint4* p = (uint4*)(act + off);
    uint4 v = *p;
    unsigned int w[4] = {v.x, v.y, v.z, v.w};
#pragma unroll
    for (int i = 0; i < 4; i++) {
        float lo = bf2f((unsigned short)(w[i] & 0xFFFFu));
        float hi = bf2f((unsigned short)(w[i] >> 16));
        lo = fmaf(lo, a, c2); lo = fmaxf(lo, 0.01f * lo);
        hi = fmaf(hi, a, c2); hi = fmaxf(hi, 0.01f * hi);
        w[i] = (unsigned int)f2bf(lo) | ((unsigned int)f2bf(hi) << 16);
    }
    uint4 r = {w[0], w[1], w[2], w[3]};
    *p = r;
}

// pooled max -> normalize -> fc1+lrelu -> fc2
__global__ __launch_bounds__(64) void fc_head(
    const float* __restrict__ pmax, const float* __restrict__ sums3, float count,
    const float* __restrict__ w_fc1, const float* __restrict__ b_fc1,
    const float* __restrict__ w_fc2, const float* __restrict__ b_fc2,
    float* __restrict__ y)
{
    const int b = blockIdx.x, t = threadIdx.x;
    __shared__ float pooled[64];
    __shared__ float hid[32];
    float2 s = stats_from(sums3, b, count);
    pooled[t] = (pmax[(size_t)b * 64 + t] - s.x) * s.y;
    __syncthreads();
    if (t < 32) {
        float h = b_fc1[t];
#pragma unroll
        for (int c = 0; c < 64; c++) h += pooled[c] * w_fc1[t * 64 + c];
        hid[t] = LRELU(h);
    }
    __syncthreads();
    if (t == 0) {
        float v = b_fc2[0];
#pragma unroll
        for (int c = 0; c < 32; c++) v += hid[c] * w_fc2[c];
        y[b] = v;
    }
}

__global__ void sigmoid_diff(const float* __restrict__ y1,
                             const float* __restrict__ y2,
                             float* __restrict__ out)
{
    int b = threadIdx.x;
    if (b < 128) out[b] = 1.0f / (1.0f + expf(-(y1[b] - y2[b])));
}

extern "C" void kernel_launch(void* const* d_in, const int* in_sizes, int n_in,
                              void* d_out, int out_size, void* d_ws, size_t ws_size,
                              hipStream_t stream)
{
    const float* data1 = (const float*)d_in[0];
    const int*   idx1  = (const int*)d_in[1];
    const float* data2 = (const float*)d_in[2];
    const int*   idx2  = (const int*)d_in[3];
    const float* w1 = (const float*)d_in[4];
    const float* b1 = (const float*)d_in[5];
    const float* w2 = (const float*)d_in[6];
    const float* b2 = (const float*)d_in[7];
    const float* w3 = (const float*)d_in[8];
    const float* b3 = (const float*)d_in[9];
    const float* wfc1 = (const float*)d_in[10];
    const float* bfc1 = (const float*)d_in[11];
    const float* wfc2 = (const float*)d_in[12];
    const float* bfc2 = (const float*)d_in[13];

    const size_t needM = (size_t)256 * 1024 * (64 + 256 + 128) * 2 + 768 * 1024;
    const bool merged = ws_size >= needM;
    const int nB = merged ? 256 : 128;
    const size_t szXT = (size_t)nB * 1024 * 64 * 2;
    const size_t szA1 = (size_t)nB * 1024 * 256 * 2;
    const size_t szA2 = (size_t)nB * 1024 * 128 * 2;

    char* ws = (char*)d_ws;
    unsigned short* xT = (unsigned short*)ws;
    unsigned short* a1 = (unsigned short*)(ws + szXT);
    unsigned short* a2 = (unsigned short*)(ws + szXT + szA1);
    char* tail = ws + szXT + szA1 + szA2;
    unsigned short* wq1 = (unsigned short*)tail;                 // 96 KB
    unsigned short* wq2 = (unsigned short*)(tail + 128 * 1024);  // 192 KB
    unsigned short* wq3 = (unsigned short*)(tail + 384 * 1024);  // 48 KB
    float* sums = (float*)(tail + 448 * 1024);                   // 3*nB*2 f32
    float* pmax = (float*)(tail + 512 * 1024);                   // nB*64 f32
    float* yv   = (float*)(tail + 640 * 1024);                   // 256 f32

    prep_weights<<<96, 256, 0, stream>>>(w1, wq1, 256, 64);
    prep_weights<<<96, 256, 0, stream>>>(w2, wq2, 128, 256);
    prep_weights<<<96, 256, 0, stream>>>(w3, wq3, 64, 128);

    const int nIter = merged ? 1 : 2;
    for (int t = 0; t < nIter; ++t) {
        const float* dA = (merged || t == 0) ? data1 : data2;
        const float* dB = merged ? data2 : dA;
        const int* iA = (merged || t == 0) ? idx1 : idx2;
        const int* iB = merged ? idx2 : iA;

        hipMemsetAsync(sums, 0, 3 * (size_t)nB * 2 * sizeof(float), stream);
        hipMemsetAsync(pmax, 0xFF, (size_t)nB * 64 * sizeof(float), stream);

        transpose_in<<<dim3(16, nB), 256, 0, stream>>>(dA, dB, xT);

        conv_mfma<128, false><<<dim3(nB, 2, 8), 256, 0, stream>>>(
            xT, iA, iB, wq1, b1, a1, sums + 0, nullptr, 64, 6, 256, 192);
        normalize_act<<<dim3(128, nB), 256, 0, stream>>>(a1, sums + 0,
                                                         256.0f * 1024.0f, 256);

        conv_mfma<128, false><<<dim3(nB, 1, 8), 256, 0, stream>>>(
            a1, iA, iB, wq2, b2, a2, sums + nB * 2, nullptr, 256, 8, 128, 768);
        normalize_act<<<dim3(64, nB), 256, 0, stream>>>(a2, sums + nB * 2,
                                                        128.0f * 1024.0f, 128);

        conv_mfma<64, true><<<dim3(nB, 1, 8), 256, 0, stream>>>(
            a2, iA, iB, wq3, b3, nullptr, sums + nB * 4, pmax, 128, 7, 64, 384);

        fc_head<<<nB, 64, 0, stream>>>(pmax, sums + nB * 4, 64.0f * 1024.0f,
                                       wfc1, bfc1, wfc2, bfc2,
                                       yv + (merged ? 0 : t * 128));
    }
    sigmoid_diff<<<1, 128, 0, stream>>>(yv, yv + 128, (float*)d_out);
}

// Round 8
// 338.594 us; speedup vs baseline: 2.1447x; 2.1447x over previous
//
#include <hip/hip_runtime.h>
#include <math.h>

typedef __attribute__((ext_vector_type(8))) short short8;
typedef __attribute__((ext_vector_type(4))) float f32x4;

#define LRELU(x) ((x) > 0.0f ? (x) : 0.01f * (x))

__device__ __forceinline__ float bf2f(unsigned short h) {
    return __uint_as_float(((unsigned int)h) << 16);
}
__device__ __forceinline__ unsigned short f2bf(float f) {
    unsigned int u = __float_as_uint(f);
    return (unsigned short)((u + 0x7FFFu + ((u >> 16) & 1u)) >> 16);
}
__device__ __forceinline__ float2 stats_from(const float* sums, int b, float count) {
    float s = sums[2 * b], q = sums[2 * b + 1];
    float mean = s / count;
    float var = (q - s * s / count) / (count - 1.0f);  // ddof=1
    var = fmaxf(var, 0.0f);
    return make_float2(mean, 1.0f / (sqrtf(var) + 1e-5f));
}
// init pattern 0xFFFFFFFF (-NaN): positives via signed max, negatives via unsigned min
__device__ __forceinline__ void atomicMaxF(float* a, float v) {
    if (v >= 0.0f) atomicMax((int*)a, __float_as_int(v));
    else           atomicMin((unsigned int*)a, __float_as_uint(v));
}
// y = lrelu(x * a + c) applied to a packed bf16 pair
__device__ __forceinline__ unsigned int norm_pair(unsigned int u, float a, float c) {
    float lo = bf2f((unsigned short)(u & 0xFFFFu));
    float hi = bf2f((unsigned short)(u >> 16));
    lo = fmaf(lo, a, c); lo = fmaxf(lo, 0.01f * lo);
    hi = fmaf(hi, a, c); hi = fmaxf(hi, 0.01f * hi);
    return (unsigned int)f2bf(lo) | ((unsigned int)f2bf(hi) << 16);
}
__device__ __forceinline__ uint4 norm8(uint4 v, float a, float c) {
    v.x = norm_pair(v.x, a, c); v.y = norm_pair(v.y, a, c);
    v.z = norm_pair(v.z, a, c); v.w = norm_pair(v.w, a, c);
    return v;
}

// w [O][Cin][3] f32  ->  wq [O][3*Cin] bf16 with k' = j*Cin + c
__global__ void prep_weights(const float* __restrict__ w, unsigned short* __restrict__ wq,
                             int O, int Cin)
{
    const int K = 3 * Cin, total = O * K;
    for (int i = blockIdx.x * blockDim.x + threadIdx.x; i < total;
         i += gridDim.x * blockDim.x) {
        int o = i / K, kp = i - o * K;
        int j = kp / Cin, c = kp - j * Cin;
        wq[i] = f2bf(w[(o * Cin + c) * 3 + j]);
    }
}

// data [128][64][1024] f32 -> xT [nB][1024][64] bf16 (tower select on b>=128)
__global__ __launch_bounds__(256) void transpose_in(const float* __restrict__ inA,
                                                    const float* __restrict__ inB,
                                                    unsigned short* __restrict__ xT)
{
    const int b = blockIdx.y, n0 = blockIdx.x * 64;
    const float* in = (b >= 128 ? inB : inA) + ((size_t)(b & 127) * 64) * 1024;
    const int tid = threadIdx.x;
    __shared__ float tile[64][65];
    const int nn = tid & 63, cw = tid >> 6;
#pragma unroll
    for (int i = 0; i < 16; i++) {
        int c = i * 4 + cw;
        tile[c][nn] = in[(size_t)c * 1024 + n0 + nn];
    }
    __syncthreads();
    const int n = tid >> 2, cp = (tid & 3) * 16;
    unsigned int pk[8];
#pragma unroll
    for (int i = 0; i < 8; i++) {
        unsigned short lo = f2bf(tile[cp + 2 * i][n]);
        unsigned short hi = f2bf(tile[cp + 2 * i + 1][n]);
        pk[i] = (unsigned int)lo | ((unsigned int)hi << 16);
    }
    unsigned short* dst = xT + ((size_t)b * 1024 + n0 + n) * 64 + cp;
    uint4 v0 = {pk[0], pk[1], pk[2], pk[3]};
    uint4 v1 = {pk[4], pk[5], pk[6], pk[7]};
    *(uint4*)dst = v0;
    *(uint4*)(dst + 8) = v1;
}

// MFMA gather-conv, register-staged pipelined K-loop.
// Staging goes global->VGPR->LDS with NAMED SCALAR uint4s (no arrays/lambdas:
// R5-R7's local arrays failed SROA and lived in scratch -> 600+ MB/dispatch of
// private-memory traffic at VGPR_Count 72-88, far under the cap).
// NORM: apply y = lrelu((x-mean)*inv) in registers during staging (replaces the
// separate normalize_act pass over the activation tensor).
template <int BM, bool POOL, bool NORM>
__global__ __launch_bounds__(256, 2) void conv_mfma(
    const unsigned short* __restrict__ xT,   // [nB][1024][Cin] bf16 (raw, pre-norm)
    const int* __restrict__ idxA,            // [128][3069]
    const int* __restrict__ idxB,
    const unsigned short* __restrict__ wq,   // [O][K] bf16 (k'=j*Cin+c)
    const float* __restrict__ bias,          // [O] f32
    unsigned short* __restrict__ out,        // [nB][1024][O] bf16 (unused if POOL)
    float* __restrict__ sums,                // [nB][2] accum (this layer's raw stats)
    float* __restrict__ pmax,                // [nB][64] (POOL only)
    const float* __restrict__ normSums,      // [nB][2] prev-layer stats (NORM only)
    float normCount, int Cin, int cinShift, int O, int K)
{
    constexpr int WM = BM / 2, MT = WM / 16;
    constexpr int NW = (BM == 128) ? 4 : 2;      // 16B packets of wt per thread
    const int b   = blockIdx.x;
    const int o0  = blockIdx.y * BM;
    const int nt0 = blockIdx.z << 7;
    const int tid = threadIdx.x;
    const int lane = tid & 63, wave = tid >> 6;
    const int wo = wave & 1, wn = wave >> 1;
    const int quad = lane >> 4, l15 = lane & 15;
    const int blkid = lane & 7;

    __shared__ __align__(16) unsigned short wt[BM * 64];
    __shared__ __align__(16) unsigned short gt[128 * 64];

    f32x4 acc[MT][4];
#pragma unroll
    for (int i = 0; i < MT; i++)
#pragma unroll
        for (int t = 0; t < 4; t++) acc[i][t] = (f32x4){0.f, 0.f, 0.f, 0.f};

    const unsigned short* xTb = xT + (((size_t)b) << 10) * (size_t)Cin;
    const int* idxb = (b >= 128 ? idxB : idxA) + (size_t)(b & 127) * 3069;

    float na = 1.0f, nc = 0.0f;
    if (NORM) {
        float2 st = stats_from(normSums, b, normCount);
        na = st.y; nc = -st.x * st.y;
    }

    // --- staging mapping ---
    const int gr = tid >> 1, gh = tid & 1;       // gt row (n), 32-elem half
    int s0, s1, s2;
    {
        int n = nt0 + gr;
        int t0 = (n == 0) ? 0 : (n - 1);         // n==0 row is garbage, zeroed later
        s0 = idxb[3 * t0]; s1 = idxb[3 * t0 + 1]; s2 = idxb[3 * t0 + 2];
    }
    const int wr   = (BM == 128) ? (tid >> 1) : (tid >> 2);  // wt row (o)
    const int wseg = (BM == 128) ? (tid & 1) : (tid & 3);    // segment of NW packets
    const unsigned short* wrow = wq + (size_t)(o0 + wr) * K + wseg * (NW * 8);
    const int gswz = gr & 7, wswz = wr & 7;

    uint4 g0, g1, g2, g3, w0, w1, w2, w3;

#define LOADC(KC) {                                                              \
        const int k64_ = (KC) << 6;                                              \
        const int j_   = k64_ >> cinShift;                                       \
        const int c0_  = k64_ & (Cin - 1);                                       \
        const int src_ = (j_ == 0) ? s0 : ((j_ == 1) ? s1 : s2);                 \
        const uint4* gp_ = (const uint4*)(xTb + (size_t)src_ * Cin + c0_ + gh * 32); \
        g0 = gp_[0]; g1 = gp_[1]; g2 = gp_[2]; g3 = gp_[3];                      \
        const uint4* wp_ = (const uint4*)(wrow + k64_);                          \
        w0 = wp_[0]; w1 = wp_[1];                                                \
        if (NW == 4) { w2 = wp_[2]; w3 = wp_[3]; }                               \
    }

#define STAGE() {                                                                \
        uint4 h0 = g0, h1 = g1, h2 = g2, h3 = g3;                                \
        if (NORM) {                                                              \
            h0 = norm8(h0, na, nc); h1 = norm8(h1, na, nc);                      \
            h2 = norm8(h2, na, nc); h3 = norm8(h3, na, nc);                      \
        }                                                                        \
        *(uint4*)&gt[gr * 64 + (((gh << 2) | 0) ^ gswz) * 8] = h0;               \
        *(uint4*)&gt[gr * 64 + (((gh << 2) | 1) ^ gswz) * 8] = h1;               \
        *(uint4*)&gt[gr * 64 + (((gh << 2) | 2) ^ gswz) * 8] = h2;               \
        *(uint4*)&gt[gr * 64 + (((gh << 2) | 3) ^ gswz) * 8] = h3;               \
        *(uint4*)&wt[wr * 64 + ((wseg * NW + 0) ^ wswz) * 8] = w0;               \
        *(uint4*)&wt[wr * 64 + ((wseg * NW + 1) ^ wswz) * 8] = w1;               \
        if (NW == 4) {                                                           \
            *(uint4*)&wt[wr * 64 + ((wseg * NW + 2) ^ wswz) * 8] = w2;           \
            *(uint4*)&wt[wr * 64 + ((wseg * NW + 3) ^ wswz) * 8] = w3;           \
        }                                                                        \
    }

    const int nChunks = K >> 6;
    LOADC(0);
    for (int kc = 0; kc < nChunks; ++kc) {
        if (kc) __syncthreads();        // prior chunk's readers done
        STAGE();                        // waits in-flight loads, writes LDS
        if (kc + 1 < nChunks) LOADC(kc + 1);  // prefetch stays in flight past barrier
        __syncthreads();                // staged data visible
#pragma unroll
        for (int st = 0; st < 2; ++st) {
            short8 af[MT], bfv[4];
            const int qb = st * 4 + quad;
#pragma unroll
            for (int i = 0; i < MT; i++) {
                const int orow = wo * WM + i * 16 + l15;
                af[i] = *(const short8*)&wt[orow * 64 + ((qb ^ blkid) << 3)];
            }
#pragma unroll
            for (int t = 0; t < 4; t++) {
                const int nrow = wn * 64 + t * 16 + l15;
                bfv[t] = *(const short8*)&gt[nrow * 64 + ((qb ^ blkid) << 3)];
            }
#pragma unroll
            for (int i = 0; i < MT; i++)
#pragma unroll
                for (int t = 0; t < 4; t++)
                    acc[i][t] = __builtin_amdgcn_mfma_f32_16x16x32_bf16(
                        af[i], bfv[t], acc[i][t], 0, 0, 0);
        }
    }
#undef LOADC
#undef STAGE

    // epilogue: bias, zero col 0, store (unless POOL), fused stats, fused max-pool
    float lsum = 0.f, lsq = 0.f;
#pragma unroll
    for (int i = 0; i < MT; i++) {
        const int ob = o0 + wo * WM + i * 16 + quad * 4;
        const float4 bv = *(const float4*)(bias + ob);
        float mx0 = -1e30f, mx1 = -1e30f, mx2 = -1e30f, mx3 = -1e30f;
#pragma unroll
        for (int t = 0; t < 4; t++) {
            const int n = nt0 + wn * 64 + t * 16 + l15;
            float v0 = acc[i][t][0] + bv.x;
            float v1 = acc[i][t][1] + bv.y;
            float v2 = acc[i][t][2] + bv.z;
            float v3 = acc[i][t][3] + bv.w;
            if (n == 0) { v0 = v1 = v2 = v3 = 0.f; }
            lsum += v0 + v1 + v2 + v3;
            lsq  += v0 * v0 + v1 * v1 + v2 * v2 + v3 * v3;
            if (POOL) {
                mx0 = fmaxf(mx0, v0); mx1 = fmaxf(mx1, v1);
                mx2 = fmaxf(mx2, v2); mx3 = fmaxf(mx3, v3);
            } else {
                ushort4 pk;
                pk.x = f2bf(v0); pk.y = f2bf(v1); pk.z = f2bf(v2); pk.w = f2bf(v3);
                *(ushort4*)&out[((size_t)b * 1024 + n) * O + ob] = pk;
            }
        }
        if (POOL) {
#pragma unroll
            for (int off = 1; off < 16; off <<= 1) {
                mx0 = fmaxf(mx0, __shfl_xor(mx0, off));
                mx1 = fmaxf(mx1, __shfl_xor(mx1, off));
                mx2 = fmaxf(mx2, __shfl_xor(mx2, off));
                mx3 = fmaxf(mx3, __shfl_xor(mx3, off));
            }
            if (l15 == 0) {
                atomicMaxF(&pmax[(size_t)b * 64 + ob + 0], mx0);
                atomicMaxF(&pmax[(size_t)b * 64 + ob + 1], mx1);
                atomicMaxF(&pmax[(size_t)b * 64 + ob + 2], mx2);
                atomicMaxF(&pmax[(size_t)b * 64 + ob + 3], mx3);
            }
        }
    }
#pragma unroll
    for (int off = 32; off > 0; off >>= 1) {
        lsum += __shfl_down(lsum, off);
        lsq  += __shfl_down(lsq, off);
    }
    float* red = (float*)wt;  // wt dead after K-loop
    if (lane == 0) { red[wave] = lsum; red[4 + wave] = lsq; }
    __syncthreads();
    if (tid == 0) {
        atomicAdd(&sums[2 * b + 0], red[0] + red[1] + red[2] + red[3]);
        atomicAdd(&sums[2 * b + 1], red[4] + red[5] + red[6] + red[7]);
    }
}

// pooled max -> normalize -> fc1+lrelu -> fc2
__global__ __launch_bounds__(64) void fc_head(
    const float* __restrict__ pmax, const float* __restrict__ sums3, float count,
    const float* __restrict__ w_fc1, const float* __restrict__ b_fc1,
    const float* __restrict__ w_fc2, const float* __restrict__ b_fc2,
    float* __restrict__ y)
{
    const int b = blockIdx.x, t = threadIdx.x;
    __shared__ float pooled[64];
    __shared__ float hid[32];
    float2 s = stats_from(sums3, b, count);
    pooled[t] = (pmax[(size_t)b * 64 + t] - s.x) * s.y;
    __syncthreads();
    if (t < 32) {
        float h = b_fc1[t];
#pragma unroll
        for (int c = 0; c < 64; c++) h += pooled[c] * w_fc1[t * 64 + c];
        hid[t] = LRELU(h);
    }
    __syncthreads();
    if (t == 0) {
        float v = b_fc2[0];
#pragma unroll
        for (int c = 0; c < 32; c++) v += hid[c] * w_fc2[c];
        y[b] = v;
    }
}

__global__ void sigmoid_diff(const float* __restrict__ y1,
                             const float* __restrict__ y2,
                             float* __restrict__ out)
{
    int b = threadIdx.x;
    if (b < 128) out[b] = 1.0f / (1.0f + expf(-(y1[b] - y2[b])));
}

extern "C" void kernel_launch(void* const* d_in, const int* in_sizes, int n_in,
                              void* d_out, int out_size, void* d_ws, size_t ws_size,
                              hipStream_t stream)
{
    const float* data1 = (const float*)d_in[0];
    const int*   idx1  = (const int*)d_in[1];
    const float* data2 = (const float*)d_in[2];
    const int*   idx2  = (const int*)d_in[3];
    const float* w1 = (const float*)d_in[4];
    const float* b1 = (const float*)d_in[5];
    const float* w2 = (const float*)d_in[6];
    const float* b2 = (const float*)d_in[7];
    const float* w3 = (const float*)d_in[8];
    const float* b3 = (const float*)d_in[9];
    const float* wfc1 = (const float*)d_in[10];
    const float* bfc1 = (const float*)d_in[11];
    const float* wfc2 = (const float*)d_in[12];
    const float* bfc2 = (const float*)d_in[13];

    const size_t needM = (size_t)256 * 1024 * (64 + 256 + 128) * 2 + 768 * 1024;
    const bool merged = ws_size >= needM;
    const int nB = merged ? 256 : 128;
    const size_t szXT = (size_t)nB * 1024 * 64 * 2;
    const size_t szA1 = (size_t)nB * 1024 * 256 * 2;
    const size_t szA2 = (size_t)nB * 1024 * 128 * 2;

    char* ws = (char*)d_ws;
    unsigned short* xT = (unsigned short*)ws;
    unsigned short* a1 = (unsigned short*)(ws + szXT);
    unsigned short* a2 = (unsigned short*)(ws + szXT + szA1);
    char* tail = ws + szXT + szA1 + szA2;
    unsigned short* wq1 = (unsigned short*)tail;                 // 96 KB
    unsigned short* wq2 = (unsigned short*)(tail + 128 * 1024);  // 192 KB
    unsigned short* wq3 = (unsigned short*)(tail + 384 * 1024);  // 48 KB
    float* sums = (float*)(tail + 448 * 1024);                   // 3*nB*2 f32
    float* pmax = (float*)(tail + 512 * 1024);                   // nB*64 f32
    float* yv   = (float*)(tail + 640 * 1024);                   // 256 f32

    prep_weights<<<96, 256, 0, stream>>>(w1, wq1, 256, 64);
    prep_weights<<<96, 256, 0, stream>>>(w2, wq2, 128, 256);
    prep_weights<<<96, 256, 0, stream>>>(w3, wq3, 64, 128);

    const int nIter = merged ? 1 : 2;
    for (int t = 0; t < nIter; ++t) {
        const float* dA = (merged || t == 0) ? data1 : data2;
        const float* dB = merged ? data2 : dA;
        const int* iA = (merged || t == 0) ? idx1 : idx2;
        const int* iB = merged ? idx2 : iA;
        float* s1 = sums;
        float* s2 = sums + nB * 2;
        float* s3 = sums + nB * 4;

        hipMemsetAsync(sums, 0, 3 * (size_t)nB * 2 * sizeof(float), stream);
        hipMemsetAsync(pmax, 0xFF, (size_t)nB * 64 * sizeof(float), stream);

        transpose_in<<<dim3(16, nB), 256, 0, stream>>>(dA, dB, xT);

        conv_mfma<128, false, false><<<dim3(nB, 2, 8), 256, 0, stream>>>(
            xT, iA, iB, wq1, b1, a1, s1, nullptr, nullptr, 0.0f, 64, 6, 256, 192);

        conv_mfma<128, false, true><<<dim3(nB, 1, 8), 256, 0, stream>>>(
            a1, iA, iB, wq2, b2, a2, s2, nullptr, s1, 256.0f * 1024.0f, 256, 8, 128, 768);

        conv_mfma<64, true, true><<<dim3(nB, 1, 8), 256, 0, stream>>>(
            a2, iA, iB, wq3, b3, nullptr, s3, pmax, s2, 128.0f * 1024.0f, 128, 7, 64, 384);

        fc_head<<<nB, 64, 0, stream>>>(pmax, s3, 64.0f * 1024.0f,
                                       wfc1, bfc1, wfc2, bfc2,
                                       yv + (merged ? 0 : t * 128));
    }
    sigmoid_diff<<<1, 128, 0, stream>>>(yv, yv + 128, (float*)d_out);
}